// Round 4
// baseline (1041.154 us; speedup 1.0000x reference)
//
#include <hip/hip_runtime.h>
#include <hip/hip_bf16.h>
#include <stdint.h>

// Round 4: flash occupancy attack. 256 Q-rows/block (512 thr, 8 waves) halves
// total KV staging; KV-split x2 (non-online softmax => partials add linearly:
// store unnormalized O + l per half, tiny combine kernel). LDS 68KB -> 2
// blocks/CU = 16 waves/CU (was 6). Per-wave inner loop identical to round 3.
//
// ws layout (92.3 MB, partials overlay dead regions):
//   xb      [8192][1024] bf16  @ 0         (dead after qkv  -> Op0)
//   wqkv_t  [3072][1024] bf16  @ 16777216  (dead after qkv  -> Lp)
//   wout_t  [1024][1024] bf16  @ 23068672
//   Qs      [16][4096][128]    @ 25165824  (dead after flash -> Ob)
//   Ks      [16][4096][128]    @ 41943040
//   Vt      [16][128][4096]    @ 58720256
//   Vs      [16][4096][128]    @ 75497472  (dead after vtrans -> Op1)

typedef __attribute__((ext_vector_type(8))) short short8;
typedef __attribute__((ext_vector_type(4))) float f32x4;

#define SCALE_Q 0.03125f

__device__ __forceinline__ unsigned short f2bf(float f) {
  union { float f; unsigned int u; } v;
  v.f = f;
  return (unsigned short)((v.u + 0x7fffu + ((v.u >> 16) & 1u)) >> 16);
}

__device__ __forceinline__ float bf2f(unsigned short h) {
  union { unsigned int u; float f; } v;
  v.u = ((unsigned int)h) << 16;
  return v.f;
}

__device__ __forceinline__ unsigned int pkbf2(float a, float b) {
  __hip_bfloat162 h = __float22bfloat162_rn(make_float2(a, b));
  union { __hip_bfloat162 h; unsigned int u; } c;
  c.h = h;
  return c.u;
}

__device__ __forceinline__ void gload_lds16(const void* g, void* l) {
  __builtin_amdgcn_global_load_lds(
      (const __attribute__((address_space(1))) uint32_t*)(uintptr_t)g,
      (__attribute__((address_space(3))) uint32_t*)(uintptr_t)l, 16, 0, 0);
}

__device__ __forceinline__ f32x4 zero4() {
  f32x4 z; z.x = 0.f; z.y = 0.f; z.z = 0.f; z.w = 0.f; return z;
}

// ---------------- conversions ----------------
__global__ __launch_bounds__(256) void k_cvt_x(const float* __restrict__ in,
                                               unsigned short* __restrict__ out) {
  const int t = blockIdx.x * 256 + threadIdx.x;
  const float4 v = ((const float4*)in)[t];
  ushort4 o;
  o.x = f2bf(v.x); o.y = f2bf(v.y); o.z = f2bf(v.z); o.w = f2bf(v.w);
  ((ushort4*)out)[t] = o;
}

__global__ __launch_bounds__(256) void k_cvt_wt(const float* __restrict__ w,
                                                unsigned short* __restrict__ wt,
                                                int Nn) {
  __shared__ float t[32][33];
  const int n0 = blockIdx.x << 5, k0 = blockIdx.y << 5;
  const int c = threadIdx.x & 31, r8 = threadIdx.x >> 5;
#pragma unroll
  for (int i = 0; i < 4; ++i) {
    const int r = (i << 3) + r8;
    t[r][c] = w[(long)(k0 + r) * Nn + n0 + c];
  }
  __syncthreads();
#pragma unroll
  for (int i = 0; i < 4; ++i) {
    const int r = (i << 3) + r8;
    wt[(long)(n0 + r) * 1024 + k0 + c] = f2bf(t[c][r]);
  }
}

// ---------------- QKV GEMM ----------------
__global__ __launch_bounds__(256, 2) void k_qkv_gemm(
    const unsigned short* __restrict__ A,   // [8192][1024]
    const unsigned short* __restrict__ Bt,  // [3072][1024]
    unsigned short* __restrict__ Qs, unsigned short* __restrict__ Ks,
    unsigned short* __restrict__ Vs) {
  __shared__ __align__(16) unsigned short lA[4][128][8];
  __shared__ __align__(16) unsigned short lB[4][128][8];
  const int tid = threadIdx.x;
  const int w = tid >> 6, ln = tid & 63;
  const int m15 = ln & 15, q4 = ln >> 4;
  const int wm = (w >> 1) << 6, wn = (w & 1) << 6;
  const int tn = blockIdx.x, tm = blockIdx.y;

  f32x4 acc[4][4];
#pragma unroll
  for (int i = 0; i < 4; ++i)
#pragma unroll
    for (int j = 0; j < 4; ++j) acc[i][j] = zero4();

  for (int kb = 0; kb < 1024; kb += 32) {
    __syncthreads();
#pragma unroll
    for (int c = 0; c < 2; ++c) {
      const int p = ((c * 4 + w) << 10) + (ln << 4);
      const int g = p >> 11;
      const int r = (p & 2047) >> 4;
      gload_lds16(A + ((long)tm * 128 + r) * 1024 + kb + g * 8,
                  (char*)&lA[0][0][0] + p);
      gload_lds16(Bt + ((long)tn * 128 + r) * 1024 + kb + g * 8,
                  (char*)&lB[0][0][0] + p);
    }
    __syncthreads();
    short8 afr[4], bfr[4];
#pragma unroll
    for (int i = 0; i < 4; ++i)
      afr[i] = *(const short8*)&lA[q4][wm + i * 16 + m15][0];
#pragma unroll
    for (int j = 0; j < 4; ++j)
      bfr[j] = *(const short8*)&lB[q4][wn + j * 16 + m15][0];
#pragma unroll
    for (int i = 0; i < 4; ++i)
#pragma unroll
      for (int j = 0; j < 4; ++j)
        acc[i][j] = __builtin_amdgcn_mfma_f32_16x16x32_bf16(afr[i], bfr[j],
                                                            acc[i][j], 0, 0, 0);
  }

  const int which = tn >> 3;
  const int h = tn & 7;
#pragma unroll
  for (int i = 0; i < 4; ++i) {
#pragma unroll
    for (int r = 0; r < 4; ++r) {
      const int m = (tm << 7) + wm + (i << 4) + (q4 << 2) + r;
      const int b = m >> 12, row = m & 4095;
      const long bh = b * 8 + h;
#pragma unroll
      for (int j = 0; j < 4; ++j) {
        const int dd = wn + (j << 4) + m15;
        const float val = acc[i][j][r];
        if (which == 0)
          Qs[(bh * 4096 + row) * 128 + dd] = f2bf(val * SCALE_Q);
        else if (which == 1)
          Ks[(bh * 4096 + row) * 128 + dd] = f2bf(val);
        else
          Vs[(bh * 4096 + row) * 128 + dd] = f2bf(val);
      }
    }
  }
}

// ---------------- V transpose ----------------
__global__ __launch_bounds__(256) void k_vtrans(
    const unsigned short* __restrict__ Vs, unsigned short* __restrict__ Vt) {
  __shared__ unsigned short t[64][66];
  const int n0 = blockIdx.x << 6, d0 = blockIdx.y << 6, bh = blockIdx.z;
  const int tt = threadIdx.x;
  const int nr = tt >> 2, dc = (tt & 3) << 4;
  const unsigned short* src = Vs + (((long)bh * 4096 + n0 + nr) << 7) + d0 + dc;
  *(short8*)&t[nr][dc] = *(const short8*)src;
  *(short8*)&t[nr][dc + 8] = *(const short8*)(src + 8);
  __syncthreads();
  const int dr = tt >> 2, nc = (tt & 3) << 4;
  short8 a, b;
#pragma unroll
  for (int jj = 0; jj < 8; ++jj) a[jj] = (short)t[nc + jj][dr];
#pragma unroll
  for (int jj = 0; jj < 8; ++jj) b[jj] = (short)t[nc + 8 + jj][dr];
  unsigned short* dst = Vt + (((long)bh * 128 + d0 + dr) << 12) + n0 + nc;
  *(short8*)dst = a;
  *(short8*)(dst + 8) = b;
}

// ---------------- flash attention (S^T, 256 rows/block, KV-split) -------
// grid (16 rowblk, 2 kvs, 16 bh); 512 thr = 8 waves x 32 rows. Each block
// handles kv range [kvs*2048, +2048); writes UNNORMALIZED O (bf16) + l.
__global__ __launch_bounds__(512, 4) void k_flash(
    const unsigned short* __restrict__ Qs, const unsigned short* __restrict__ Ks,
    const unsigned short* __restrict__ Vt, const int* __restrict__ mask,
    unsigned short* __restrict__ Op0, unsigned short* __restrict__ Op1,
    float* __restrict__ Lp) {
  __shared__ __align__(16) unsigned short lK[16][64][8];   // 16 KB
  __shared__ __align__(16) unsigned short lV[8][128][8];   // 16 KB
  __shared__ __align__(16) unsigned short lP[8][32][72];   // 36.9 KB

  const int tid = threadIdx.x;
  const int w = tid >> 6, ln = tid & 63;
  const int m15 = ln & 15, q4 = ln >> 4;
  const int rowblk = blockIdx.x, kvs = blockIdx.y, bh = blockIdx.z;
  const int rbase = rowblk * 256 + w * 32;

  const unsigned short* Qbh = Qs + (long)bh * 524288;
  const unsigned short* Kbh = Ks + (long)bh * 524288;
  const unsigned short* Vbh = Vt + (long)bh * 524288;
  unsigned short* Op = kvs ? Op1 : Op0;

  short8 qf[2][4];
#pragma unroll
  for (int i = 0; i < 2; ++i)
#pragma unroll
    for (int kk = 0; kk < 4; ++kk)
      qf[i][kk] = *(const short8*)(Qbh +
          (long)(rbase + i * 16 + m15) * 128 + kk * 32 + q4 * 8);

  f32x4 o[2][8];
#pragma unroll
  for (int i = 0; i < 2; ++i)
#pragma unroll
    for (int j = 0; j < 8; ++j) o[i][j] = zero4();
  f32x4 lacc[2];
  lacc[0] = zero4(); lacc[1] = zero4();

  const bool maskblk = (rowblk < 8) && (kvs == 0);
  const int kv0 = kvs << 11;

  for (int kv = kv0; kv < kv0 + 2048; kv += 64) {
    __syncthreads();
    // stage K (16KB: c=0,1) and V (16KB: c=2,3); 512 thr x 16B per c-iter
#pragma unroll
    for (int c = 0; c < 2; ++c) {
      const int p = ((c * 8 + w) << 10) + (ln << 4);
      const int cs = p >> 10;
      const int j = (p & 1023) >> 4;
      gload_lds16(Kbh + (long)(kv + j) * 128 + cs * 8, (char*)&lK[0][0][0] + p);
    }
#pragma unroll
    for (int c = 0; c < 2; ++c) {
      const int p = ((c * 8 + w) << 10) + (ln << 4);
      const int cv = p >> 11;
      const int dv = (p & 2047) >> 4;
      gload_lds16(Vbh + (long)dv * 4096 + kv + cv * 8, (char*)&lV[0][0][0] + p);
    }
    __syncthreads();

    // S^T = K Q^T : s[i][jt][r] = S[q = rbase+i*16+m15][j = kv+jt*16+q4*4+r]
    f32x4 s[2][4];
#pragma unroll
    for (int i = 0; i < 2; ++i)
#pragma unroll
      for (int jt = 0; jt < 4; ++jt) s[i][jt] = zero4();
#pragma unroll
    for (int jt = 0; jt < 4; ++jt) {
      short8 kfr[4];
#pragma unroll
      for (int kk = 0; kk < 4; ++kk)
        kfr[kk] = *(const short8*)&lK[kk * 4 + q4][jt * 16 + m15][0];
#pragma unroll
      for (int i = 0; i < 2; ++i)
#pragma unroll
        for (int kk = 0; kk < 4; ++kk)
          s[i][jt] = __builtin_amdgcn_mfma_f32_16x16x32_bf16(kfr[kk], qf[i][kk],
                                                             s[i][jt], 0, 0, 0);
    }

    if (maskblk) {
#pragma unroll
      for (int i = 0; i < 2; ++i) {
        const int qrow = rbase + i * 16 + m15;
#pragma unroll
        for (int jt = 0; jt < 4; ++jt) {
          const int4 mv =
              *(const int4*)&mask[(long)qrow * 2048 + kv + jt * 16 + q4 * 4];
          s[i][jt].x = mv.x ? s[i][jt].x : -1e30f;
          s[i][jt].y = mv.y ? s[i][jt].y : -1e30f;
          s[i][jt].z = mv.z ? s[i][jt].z : -1e30f;
          s[i][jt].w = mv.w ? s[i][jt].w : -1e30f;
        }
      }
    }

    // p = exp(s); per-lane l; pack to wave-private LDS as PV A-frags.
#pragma unroll
    for (int i = 0; i < 2; ++i) {
#pragma unroll
      for (int jt = 0; jt < 4; ++jt) {
        f32x4 p;
        p.x = __expf(s[i][jt].x); p.y = __expf(s[i][jt].y);
        p.z = __expf(s[i][jt].z); p.w = __expf(s[i][jt].w);
        lacc[i].x += p.x; lacc[i].y += p.y;
        lacc[i].z += p.z; lacc[i].w += p.w;
        uint2 u;
        u.x = pkbf2(p.x, p.y);
        u.y = pkbf2(p.z, p.w);
        *(uint2*)&lP[w][i * 16 + m15][jt * 16 + q4 * 4] = u;
      }
    }
    __asm__ volatile("s_waitcnt lgkmcnt(0)" ::: "memory");

    // O += P @ V
#pragma unroll
    for (int kk2 = 0; kk2 < 2; ++kk2) {
      short8 pf[2];
#pragma unroll
      for (int i = 0; i < 2; ++i)
        pf[i] = *(const short8*)&lP[w][i * 16 + m15][kk2 * 32 + q4 * 8];
#pragma unroll
      for (int jt2 = 0; jt2 < 8; ++jt2) {
        const short8 vf = *(const short8*)&lV[kk2 * 4 + q4][jt2 * 16 + m15][0];
#pragma unroll
        for (int i = 0; i < 2; ++i)
          o[i][jt2] = __builtin_amdgcn_mfma_f32_16x16x32_bf16(pf[i], vf,
                                                              o[i][jt2], 0, 0, 0);
      }
    }
  }

  // epilogue: unnormalized O (bf16) + per-row l (fp32, q4==0 lanes)
  const int b = bh >> 3, h = bh & 7;
#pragma unroll
  for (int i = 0; i < 2; ++i) {
    float lh = lacc[i].x + lacc[i].y + lacc[i].z + lacc[i].w;
    lh += __shfl_xor(lh, 16);
    lh += __shfl_xor(lh, 32);
    if (ln < 16)
      Lp[(((long)kvs * 16 + bh) << 12) + rbase + i * 16 + m15] = lh;
#pragma unroll
    for (int r = 0; r < 4; ++r) {
      const int row = rbase + i * 16 + q4 * 4 + r;
      unsigned short* op = Op + ((long)(b * 4096 + row)) * 1024 + h * 128;
#pragma unroll
      for (int jt2 = 0; jt2 < 8; ++jt2)
        op[jt2 * 16 + m15] = f2bf(o[i][jt2][r]);
    }
  }
}

// ---------------- combine: Ob = (O0+O1)/(l0+l1) ----------------
__global__ __launch_bounds__(256) void k_combine(
    const unsigned short* __restrict__ O0, const unsigned short* __restrict__ O1,
    const float* __restrict__ Lp, unsigned short* __restrict__ Ob) {
  const long t = (long)blockIdx.x * 256 + threadIdx.x;
  const long idx = t << 3;
  const int m = (int)(idx >> 10), col = (int)(idx & 1023);
  const int b = m >> 12, row = m & 4095, h = col >> 7;
  const long li = (((long)(b * 8 + h)) << 12) + row;
  const float linv = 1.0f / (Lp[li] + Lp[li + (16L << 12)]);
  const short8 a = *(const short8*)(O0 + idx);
  const short8 c = *(const short8*)(O1 + idx);
  short8 o;
#pragma unroll
  for (int k = 0; k < 8; ++k)
    o[k] = (short)f2bf((bf2f((unsigned short)a[k]) +
                        bf2f((unsigned short)c[k])) * linv);
  *(short8*)(Ob + idx) = o;
}

// ---------------- out projection ----------------
__global__ __launch_bounds__(256, 2) void k_proj_gemm(
    const unsigned short* __restrict__ A,   // [8192][1024]
    const unsigned short* __restrict__ Bt,  // [1024][1024]
    const float* __restrict__ bias, float* __restrict__ Out) {
  __shared__ __align__(16) unsigned short lA[4][128][8];
  __shared__ __align__(16) unsigned short lB[4][128][8];
  const int tid = threadIdx.x;
  const int w = tid >> 6, ln = tid & 63;
  const int m15 = ln & 15, q4 = ln >> 4;
  const int wm = (w >> 1) << 6, wn = (w & 1) << 6;
  const int tn = blockIdx.x, tm = blockIdx.y;

  f32x4 acc[4][4];
#pragma unroll
  for (int i = 0; i < 4; ++i)
#pragma unroll
    for (int j = 0; j < 4; ++j) acc[i][j] = zero4();

  for (int kb = 0; kb < 1024; kb += 32) {
    __syncthreads();
#pragma unroll
    for (int c = 0; c < 2; ++c) {
      const int p = ((c * 4 + w) << 10) + (ln << 4);
      const int g = p >> 11;
      const int r = (p & 2047) >> 4;
      gload_lds16(A + ((long)tm * 128 + r) * 1024 + kb + g * 8,
                  (char*)&lA[0][0][0] + p);
      gload_lds16(Bt + ((long)tn * 128 + r) * 1024 + kb + g * 8,
                  (char*)&lB[0][0][0] + p);
    }
    __syncthreads();
    short8 afr[4], bfr[4];
#pragma unroll
    for (int i = 0; i < 4; ++i)
      afr[i] = *(const short8*)&lA[q4][wm + i * 16 + m15][0];
#pragma unroll
    for (int j = 0; j < 4; ++j)
      bfr[j] = *(const short8*)&lB[q4][wn + j * 16 + m15][0];
#pragma unroll
    for (int i = 0; i < 4; ++i)
#pragma unroll
      for (int j = 0; j < 4; ++j)
        acc[i][j] = __builtin_amdgcn_mfma_f32_16x16x32_bf16(afr[i], bfr[j],
                                                            acc[i][j], 0, 0, 0);
  }

#pragma unroll
  for (int i = 0; i < 4; ++i)
#pragma unroll
    for (int r = 0; r < 4; ++r) {
      const int m = (tm << 7) + wm + (i << 4) + (q4 << 2) + r;
#pragma unroll
      for (int j = 0; j < 4; ++j) {
        const int n = (tn << 7) + wn + (j << 4) + m15;
        Out[(long)m * 1024 + n] = acc[i][j][r] + bias[n];
      }
    }
}

extern "C" void kernel_launch(void* const* d_in, const int* in_sizes, int n_in,
                              void* d_out, int out_size, void* d_ws,
                              size_t ws_size, hipStream_t stream) {
  const float* x = (const float*)d_in[0];
  const float* Wqkv = (const float*)d_in[1];
  const float* Wout = (const float*)d_in[2];
  const float* bout = (const float*)d_in[3];
  const int* mask = (const int*)d_in[4];
  float* out = (float*)d_out;

  char* ws = (char*)d_ws;
  unsigned short* xb     = (unsigned short*)(ws);            // later Op0
  unsigned short* wqkv_t = (unsigned short*)(ws + 16777216); // later Lp
  unsigned short* wout_t = (unsigned short*)(ws + 23068672);
  unsigned short* Qs     = (unsigned short*)(ws + 25165824); // later Ob
  unsigned short* Ks     = (unsigned short*)(ws + 41943040);
  unsigned short* Vt     = (unsigned short*)(ws + 58720256);
  unsigned short* Vs     = (unsigned short*)(ws + 75497472); // later Op1

  unsigned short* Op0 = xb;
  unsigned short* Op1 = Vs;
  float*          Lp  = (float*)wqkv_t;
  unsigned short* Ob  = Qs;

  hipLaunchKernelGGL(k_cvt_x, dim3(8192), dim3(256), 0, stream, x, xb);
  hipLaunchKernelGGL(k_cvt_wt, dim3(96, 32), dim3(256), 0, stream, Wqkv, wqkv_t, 3072);
  hipLaunchKernelGGL(k_cvt_wt, dim3(32, 32), dim3(256), 0, stream, Wout, wout_t, 1024);
  hipLaunchKernelGGL(k_qkv_gemm, dim3(24, 64), dim3(256), 0, stream,
                     xb, wqkv_t, Qs, Ks, Vs);
  hipLaunchKernelGGL(k_vtrans, dim3(64, 2, 16), dim3(256), 0, stream, Vs, Vt);
  hipLaunchKernelGGL(k_flash, dim3(16, 2, 16), dim3(512), 0, stream,
                     Qs, Ks, Vt, mask, Op0, Op1, Lp);
  hipLaunchKernelGGL(k_combine, dim3(4096), dim3(256), 0, stream,
                     Op0, Op1, Lp, Ob);
  hipLaunchKernelGGL(k_proj_gemm, dim3(8, 64), dim3(256), 0, stream,
                     Ob, wout_t, bout, out);
}

// Round 5
// 541.866 us; speedup vs baseline: 1.9214x; 1.9214x over previous
//
#include <hip/hip_runtime.h>
#include <hip/hip_bf16.h>
#include <stdint.h>

// Round 5: flash keeps round-3's register shape (256 thr, 168 regs/wave ->
// 3 waves/SIMD fits; round 4's 512-thr launch_bounds(512,4) spilled the
// 64-AGPR O-accumulator to scratch = 2.5 GB HBM traffic). Occupancy instead
// via KV-split x2 in the GRID: 1024 blocks x 50KB LDS -> 3 blocks/CU =
// 12 waves/CU (was 8). Non-online softmax => halves combine linearly.
// qkv_gemm: Q/K tiles use swapped mfma (C^T) -> packed 8B stores; V tiles
// normal orientation -> reg-quad is Vt's fast axis -> writes Vt directly
// (Vs + k_vtrans eliminated).
//
// ws layout (92.3 MB, partials overlay dead regions):
//   xb      [8192][1024] bf16  @ 0         (dead after qkv  -> Op0)
//   wqkv_t  [3072][1024] bf16  @ 16777216  (dead after qkv  -> Lp)
//   wout_t  [1024][1024] bf16  @ 23068672
//   Qs      [16][4096][128]    @ 25165824  (dead after flash -> Ob)
//   Ks      [16][4096][128]    @ 41943040
//   Vt      [16][128][4096]    @ 58720256
//   Op1     [8192][1024] bf16  @ 75497472

typedef __attribute__((ext_vector_type(8))) short short8;
typedef __attribute__((ext_vector_type(4))) float f32x4;

#define SCALE_Q 0.03125f

__device__ __forceinline__ unsigned short f2bf(float f) {
  union { float f; unsigned int u; } v;
  v.f = f;
  return (unsigned short)((v.u + 0x7fffu + ((v.u >> 16) & 1u)) >> 16);
}

__device__ __forceinline__ float bf2f(unsigned short h) {
  union { unsigned int u; float f; } v;
  v.u = ((unsigned int)h) << 16;
  return v.f;
}

__device__ __forceinline__ unsigned int pkbf2(float a, float b) {
  __hip_bfloat162 h = __float22bfloat162_rn(make_float2(a, b));
  union { __hip_bfloat162 h; unsigned int u; } c;
  c.h = h;
  return c.u;
}

__device__ __forceinline__ void gload_lds16(const void* g, void* l) {
  __builtin_amdgcn_global_load_lds(
      (const __attribute__((address_space(1))) uint32_t*)(uintptr_t)g,
      (__attribute__((address_space(3))) uint32_t*)(uintptr_t)l, 16, 0, 0);
}

__device__ __forceinline__ f32x4 zero4() {
  f32x4 z; z.x = 0.f; z.y = 0.f; z.z = 0.f; z.w = 0.f; return z;
}

// ---------------- conversions ----------------
__global__ __launch_bounds__(256) void k_cvt_x(const float* __restrict__ in,
                                               unsigned short* __restrict__ out) {
  const int t = blockIdx.x * 256 + threadIdx.x;
  const float4 v = ((const float4*)in)[t];
  ushort4 o;
  o.x = f2bf(v.x); o.y = f2bf(v.y); o.z = f2bf(v.z); o.w = f2bf(v.w);
  ((ushort4*)out)[t] = o;
}

__global__ __launch_bounds__(256) void k_cvt_wt(const float* __restrict__ w,
                                                unsigned short* __restrict__ wt,
                                                int Nn) {
  __shared__ float t[32][33];
  const int n0 = blockIdx.x << 5, k0 = blockIdx.y << 5;
  const int c = threadIdx.x & 31, r8 = threadIdx.x >> 5;
#pragma unroll
  for (int i = 0; i < 4; ++i) {
    const int r = (i << 3) + r8;
    t[r][c] = w[(long)(k0 + r) * Nn + n0 + c];
  }
  __syncthreads();
#pragma unroll
  for (int i = 0; i < 4; ++i) {
    const int r = (i << 3) + r8;
    wt[(long)(n0 + r) * 1024 + k0 + c] = f2bf(t[c][r]);
  }
}

// ---------------- QKV GEMM ----------------
// Q/K tiles: acc^T = mfma(bfr, afr) -> lane reg-quad = 4 consecutive d ->
// packed 8B stores to Qs/Ks. V tiles: normal acc = mfma(afr, bfr) -> lane
// reg-quad = 4 consecutive m (= Vt fast axis n) -> packed 8B stores to Vt.
__global__ __launch_bounds__(256, 2) void k_qkv_gemm(
    const unsigned short* __restrict__ A,   // [8192][1024]
    const unsigned short* __restrict__ Bt,  // [3072][1024]
    unsigned short* __restrict__ Qs, unsigned short* __restrict__ Ks,
    unsigned short* __restrict__ Vt) {
  __shared__ __align__(16) unsigned short lA[4][128][8];
  __shared__ __align__(16) unsigned short lB[4][128][8];
  const int tid = threadIdx.x;
  const int w = tid >> 6, ln = tid & 63;
  const int m15 = ln & 15, q4 = ln >> 4;
  const int wm = (w >> 1) << 6, wn = (w & 1) << 6;
  const int tn = blockIdx.x, tm = blockIdx.y;
  const int which = tn >> 3;   // 0=Q 1=K 2=V (uniform per block)
  const int h = tn & 7;

  f32x4 acc[4][4];
#pragma unroll
  for (int i = 0; i < 4; ++i)
#pragma unroll
    for (int j = 0; j < 4; ++j) acc[i][j] = zero4();

  if (which == 2) {
    // ---- normal orientation: acc[i][j] = C[m-block i][n-block j] ----
    for (int kb = 0; kb < 1024; kb += 32) {
      __syncthreads();
#pragma unroll
      for (int c = 0; c < 2; ++c) {
        const int p = ((c * 4 + w) << 10) + (ln << 4);
        const int g = p >> 11;
        const int r = (p & 2047) >> 4;
        gload_lds16(A + ((long)tm * 128 + r) * 1024 + kb + g * 8,
                    (char*)&lA[0][0][0] + p);
        gload_lds16(Bt + ((long)tn * 128 + r) * 1024 + kb + g * 8,
                    (char*)&lB[0][0][0] + p);
      }
      __syncthreads();
      short8 afr[4], bfr[4];
#pragma unroll
      for (int i = 0; i < 4; ++i)
        afr[i] = *(const short8*)&lA[q4][wm + i * 16 + m15][0];
#pragma unroll
      for (int j = 0; j < 4; ++j)
        bfr[j] = *(const short8*)&lB[q4][wn + j * 16 + m15][0];
#pragma unroll
      for (int i = 0; i < 4; ++i)
#pragma unroll
        for (int j = 0; j < 4; ++j)
          acc[i][j] = __builtin_amdgcn_mfma_f32_16x16x32_bf16(afr[i], bfr[j],
                                                              acc[i][j], 0, 0, 0);
    }
    // V epilogue: lane quad = 4 consecutive m; dd = wn + j*16 + m15
#pragma unroll
    for (int i = 0; i < 4; ++i) {
      const int m0 = (tm << 7) + wm + (i << 4) + (q4 << 2);
      const int b = m0 >> 12, row0 = m0 & 4095;
#pragma unroll
      for (int j = 0; j < 4; ++j) {
        const int dd = wn + (j << 4) + m15;
        const long bh = b * 8 + h;
        uint2 u;
        u.x = pkbf2(acc[i][j][0], acc[i][j][1]);
        u.y = pkbf2(acc[i][j][2], acc[i][j][3]);
        *(uint2*)&Vt[(bh * 128 + dd) * 4096 + row0] = u;
      }
    }
  } else {
    // ---- swapped orientation: acc[i][j] = C^T[d-block j][m-block i] ----
    for (int kb = 0; kb < 1024; kb += 32) {
      __syncthreads();
#pragma unroll
      for (int c = 0; c < 2; ++c) {
        const int p = ((c * 4 + w) << 10) + (ln << 4);
        const int g = p >> 11;
        const int r = (p & 2047) >> 4;
        gload_lds16(A + ((long)tm * 128 + r) * 1024 + kb + g * 8,
                    (char*)&lA[0][0][0] + p);
        gload_lds16(Bt + ((long)tn * 128 + r) * 1024 + kb + g * 8,
                    (char*)&lB[0][0][0] + p);
      }
      __syncthreads();
      short8 afr[4], bfr[4];
#pragma unroll
      for (int i = 0; i < 4; ++i)
        afr[i] = *(const short8*)&lA[q4][wm + i * 16 + m15][0];
#pragma unroll
      for (int j = 0; j < 4; ++j)
        bfr[j] = *(const short8*)&lB[q4][wn + j * 16 + m15][0];
#pragma unroll
      for (int i = 0; i < 4; ++i)
#pragma unroll
        for (int j = 0; j < 4; ++j)
          acc[i][j] = __builtin_amdgcn_mfma_f32_16x16x32_bf16(bfr[j], afr[i],
                                                              acc[i][j], 0, 0, 0);
    }
    // Q/K epilogue: lane m = wm+i*16+m15, quad = 4 consecutive dd
    unsigned short* Dst = (which == 0) ? Qs : Ks;
    const float sc = (which == 0) ? SCALE_Q : 1.0f;
#pragma unroll
    for (int i = 0; i < 4; ++i) {
      const int m = (tm << 7) + wm + (i << 4) + m15;
      const int b = m >> 12, row = m & 4095;
      const long bh = b * 8 + h;
#pragma unroll
      for (int j = 0; j < 4; ++j) {
        const int dd0 = wn + (j << 4) + (q4 << 2);
        uint2 u;
        u.x = pkbf2(acc[i][j][0] * sc, acc[i][j][1] * sc);
        u.y = pkbf2(acc[i][j][2] * sc, acc[i][j][3] * sc);
        *(uint2*)&Dst[(bh * 4096 + row) * 128 + dd0] = u;
      }
    }
  }
}

// ---------------- flash attention (S^T, 128 rows/block, KV-split x2) ----
// grid (32 rowblk, 2 kvs, 16 bh); 256 thr = 4 waves x 32 rows. Each block
// covers kv in [kvs*2048, +2048); writes UNNORMALIZED O + per-row l.
__global__ __launch_bounds__(256, 2) void k_flash(
    const unsigned short* __restrict__ Qs, const unsigned short* __restrict__ Ks,
    const unsigned short* __restrict__ Vt, const int* __restrict__ mask,
    unsigned short* __restrict__ Op0, unsigned short* __restrict__ Op1,
    float* __restrict__ Lp) {
  __shared__ __align__(16) unsigned short lK[16][64][8];   // 16 KB
  __shared__ __align__(16) unsigned short lV[8][128][8];   // 16 KB
  __shared__ __align__(16) unsigned short lP[4][32][72];   // 18 KB

  const int tid = threadIdx.x;
  const int w = tid >> 6, ln = tid & 63;
  const int m15 = ln & 15, q4 = ln >> 4;
  const int rowblk = blockIdx.x, kvs = blockIdx.y, bh = blockIdx.z;
  const int rbase = rowblk * 128 + w * 32;

  const unsigned short* Qbh = Qs + (long)bh * 524288;
  const unsigned short* Kbh = Ks + (long)bh * 524288;
  const unsigned short* Vbh = Vt + (long)bh * 524288;
  unsigned short* Op = kvs ? Op1 : Op0;

  short8 qf[2][4];
#pragma unroll
  for (int i = 0; i < 2; ++i)
#pragma unroll
    for (int kk = 0; kk < 4; ++kk)
      qf[i][kk] = *(const short8*)(Qbh +
          (long)(rbase + i * 16 + m15) * 128 + kk * 32 + q4 * 8);

  f32x4 o[2][8];
#pragma unroll
  for (int i = 0; i < 2; ++i)
#pragma unroll
    for (int j = 0; j < 8; ++j) o[i][j] = zero4();
  f32x4 lacc[2];
  lacc[0] = zero4(); lacc[1] = zero4();

  const bool maskblk = (rowblk < 16) && (kvs == 0);
  const int kv0 = kvs << 11;

  for (int kv = kv0; kv < kv0 + 2048; kv += 64) {
    __syncthreads();
#pragma unroll
    for (int c = 0; c < 4; ++c) {
      const int p = ((c * 4 + w) << 10) + (ln << 4);
      const int cs = p >> 10;
      const int j = (p & 1023) >> 4;
      gload_lds16(Kbh + (long)(kv + j) * 128 + cs * 8, (char*)&lK[0][0][0] + p);
      const int cv = p >> 11;
      const int dv = (p & 2047) >> 4;
      gload_lds16(Vbh + (long)dv * 4096 + kv + cv * 8, (char*)&lV[0][0][0] + p);
    }
    __syncthreads();

    // S^T = K Q^T : s[i][jt][r] = S[q = rbase+i*16+m15][j = kv+jt*16+q4*4+r]
    f32x4 s[2][4];
#pragma unroll
    for (int i = 0; i < 2; ++i)
#pragma unroll
      for (int jt = 0; jt < 4; ++jt) s[i][jt] = zero4();
#pragma unroll
    for (int jt = 0; jt < 4; ++jt) {
      short8 kfr[4];
#pragma unroll
      for (int kk = 0; kk < 4; ++kk)
        kfr[kk] = *(const short8*)&lK[kk * 4 + q4][jt * 16 + m15][0];
#pragma unroll
      for (int i = 0; i < 2; ++i)
#pragma unroll
        for (int kk = 0; kk < 4; ++kk)
          s[i][jt] = __builtin_amdgcn_mfma_f32_16x16x32_bf16(kfr[kk], qf[i][kk],
                                                             s[i][jt], 0, 0, 0);
    }

    if (maskblk) {
#pragma unroll
      for (int i = 0; i < 2; ++i) {
        const int qrow = rbase + i * 16 + m15;
#pragma unroll
        for (int jt = 0; jt < 4; ++jt) {
          const int4 mv =
              *(const int4*)&mask[(long)qrow * 2048 + kv + jt * 16 + q4 * 4];
          s[i][jt].x = mv.x ? s[i][jt].x : -1e30f;
          s[i][jt].y = mv.y ? s[i][jt].y : -1e30f;
          s[i][jt].z = mv.z ? s[i][jt].z : -1e30f;
          s[i][jt].w = mv.w ? s[i][jt].w : -1e30f;
        }
      }
    }

    // p = exp(s); per-lane l; pack to wave-private LDS as PV A-frags.
#pragma unroll
    for (int i = 0; i < 2; ++i) {
#pragma unroll
      for (int jt = 0; jt < 4; ++jt) {
        f32x4 p;
        p.x = __expf(s[i][jt].x); p.y = __expf(s[i][jt].y);
        p.z = __expf(s[i][jt].z); p.w = __expf(s[i][jt].w);
        lacc[i].x += p.x; lacc[i].y += p.y;
        lacc[i].z += p.z; lacc[i].w += p.w;
        uint2 u;
        u.x = pkbf2(p.x, p.y);
        u.y = pkbf2(p.z, p.w);
        *(uint2*)&lP[w][i * 16 + m15][jt * 16 + q4 * 4] = u;
      }
    }
    __asm__ volatile("s_waitcnt lgkmcnt(0)" ::: "memory");

    // O += P @ V
#pragma unroll
    for (int kk2 = 0; kk2 < 2; ++kk2) {
      short8 pf[2];
#pragma unroll
      for (int i = 0; i < 2; ++i)
        pf[i] = *(const short8*)&lP[w][i * 16 + m15][kk2 * 32 + q4 * 8];
#pragma unroll
      for (int jt2 = 0; jt2 < 8; ++jt2) {
        const short8 vf = *(const short8*)&lV[kk2 * 4 + q4][jt2 * 16 + m15][0];
#pragma unroll
        for (int i = 0; i < 2; ++i)
          o[i][jt2] = __builtin_amdgcn_mfma_f32_16x16x32_bf16(pf[i], vf,
                                                              o[i][jt2], 0, 0, 0);
      }
    }
  }

  // epilogue: unnormalized O (bf16) + per-row l (fp32)
  const int b = bh >> 3, h = bh & 7;
#pragma unroll
  for (int i = 0; i < 2; ++i) {
    float lh = lacc[i].x + lacc[i].y + lacc[i].z + lacc[i].w;
    lh += __shfl_xor(lh, 16);
    lh += __shfl_xor(lh, 32);
    if (ln < 16)
      Lp[(((long)kvs * 16 + bh) << 12) + rbase + i * 16 + m15] = lh;
#pragma unroll
    for (int r = 0; r < 4; ++r) {
      const int row = rbase + i * 16 + q4 * 4 + r;
      unsigned short* op = Op + ((long)(b * 4096 + row)) * 1024 + h * 128;
#pragma unroll
      for (int jt2 = 0; jt2 < 8; ++jt2)
        op[jt2 * 16 + m15] = f2bf(o[i][jt2][r]);
    }
  }
}

// ---------------- combine: Ob = (O0+O1)/(l0+l1) ----------------
__global__ __launch_bounds__(256) void k_combine(
    const unsigned short* __restrict__ O0, const unsigned short* __restrict__ O1,
    const float* __restrict__ Lp, unsigned short* __restrict__ Ob) {
  const long t = (long)blockIdx.x * 256 + threadIdx.x;
  const long idx = t << 3;
  const int m = (int)(idx >> 10), col = (int)(idx & 1023);
  const int b = m >> 12, row = m & 4095, h = col >> 7;
  const long li = (((long)(b * 8 + h)) << 12) + row;
  const float linv = 1.0f / (Lp[li] + Lp[li + (16L << 12)]);
  const short8 a = *(const short8*)(O0 + idx);
  const short8 c = *(const short8*)(O1 + idx);
  short8 o;
#pragma unroll
  for (int k = 0; k < 8; ++k)
    o[k] = (short)f2bf((bf2f((unsigned short)a[k]) +
                        bf2f((unsigned short)c[k])) * linv);
  *(short8*)(Ob + idx) = o;
}

// ---------------- out projection ----------------
__global__ __launch_bounds__(256, 2) void k_proj_gemm(
    const unsigned short* __restrict__ A,   // [8192][1024]
    const unsigned short* __restrict__ Bt,  // [1024][1024]
    const float* __restrict__ bias, float* __restrict__ Out) {
  __shared__ __align__(16) unsigned short lA[4][128][8];
  __shared__ __align__(16) unsigned short lB[4][128][8];
  const int tid = threadIdx.x;
  const int w = tid >> 6, ln = tid & 63;
  const int m15 = ln & 15, q4 = ln >> 4;
  const int wm = (w >> 1) << 6, wn = (w & 1) << 6;
  const int tn = blockIdx.x, tm = blockIdx.y;

  f32x4 acc[4][4];
#pragma unroll
  for (int i = 0; i < 4; ++i)
#pragma unroll
    for (int j = 0; j < 4; ++j) acc[i][j] = zero4();

  for (int kb = 0; kb < 1024; kb += 32) {
    __syncthreads();
#pragma unroll
    for (int c = 0; c < 2; ++c) {
      const int p = ((c * 4 + w) << 10) + (ln << 4);
      const int g = p >> 11;
      const int r = (p & 2047) >> 4;
      gload_lds16(A + ((long)tm * 128 + r) * 1024 + kb + g * 8,
                  (char*)&lA[0][0][0] + p);
      gload_lds16(Bt + ((long)tn * 128 + r) * 1024 + kb + g * 8,
                  (char*)&lB[0][0][0] + p);
    }
    __syncthreads();
    short8 afr[4], bfr[4];
#pragma unroll
    for (int i = 0; i < 4; ++i)
      afr[i] = *(const short8*)&lA[q4][wm + i * 16 + m15][0];
#pragma unroll
    for (int j = 0; j < 4; ++j)
      bfr[j] = *(const short8*)&lB[q4][wn + j * 16 + m15][0];
#pragma unroll
    for (int i = 0; i < 4; ++i)
#pragma unroll
      for (int j = 0; j < 4; ++j)
        acc[i][j] = __builtin_amdgcn_mfma_f32_16x16x32_bf16(afr[i], bfr[j],
                                                            acc[i][j], 0, 0, 0);
  }

#pragma unroll
  for (int i = 0; i < 4; ++i)
#pragma unroll
    for (int r = 0; r < 4; ++r) {
      const int m = (tm << 7) + wm + (i << 4) + (q4 << 2) + r;
#pragma unroll
      for (int j = 0; j < 4; ++j) {
        const int n = (tn << 7) + wn + (j << 4) + m15;
        Out[(long)m * 1024 + n] = acc[i][j][r] + bias[n];
      }
    }
}

extern "C" void kernel_launch(void* const* d_in, const int* in_sizes, int n_in,
                              void* d_out, int out_size, void* d_ws,
                              size_t ws_size, hipStream_t stream) {
  const float* x = (const float*)d_in[0];
  const float* Wqkv = (const float*)d_in[1];
  const float* Wout = (const float*)d_in[2];
  const float* bout = (const float*)d_in[3];
  const int* mask = (const int*)d_in[4];
  float* out = (float*)d_out;

  char* ws = (char*)d_ws;
  unsigned short* xb     = (unsigned short*)(ws);            // later Op0
  unsigned short* wqkv_t = (unsigned short*)(ws + 16777216); // later Lp
  unsigned short* wout_t = (unsigned short*)(ws + 23068672);
  unsigned short* Qs     = (unsigned short*)(ws + 25165824); // later Ob
  unsigned short* Ks     = (unsigned short*)(ws + 41943040);
  unsigned short* Vt     = (unsigned short*)(ws + 58720256);
  unsigned short* Op1    = (unsigned short*)(ws + 75497472);

  unsigned short* Op0 = xb;
  float*          Lp  = (float*)wqkv_t;
  unsigned short* Ob  = Qs;

  hipLaunchKernelGGL(k_cvt_x, dim3(8192), dim3(256), 0, stream, x, xb);
  hipLaunchKernelGGL(k_cvt_wt, dim3(96, 32), dim3(256), 0, stream, Wqkv, wqkv_t, 3072);
  hipLaunchKernelGGL(k_cvt_wt, dim3(32, 32), dim3(256), 0, stream, Wout, wout_t, 1024);
  hipLaunchKernelGGL(k_qkv_gemm, dim3(24, 64), dim3(256), 0, stream,
                     xb, wqkv_t, Qs, Ks, Vt);
  hipLaunchKernelGGL(k_flash, dim3(32, 2, 16), dim3(256), 0, stream,
                     Qs, Ks, Vt, mask, Op0, Op1, Lp);
  hipLaunchKernelGGL(k_combine, dim3(4096), dim3(256), 0, stream,
                     Op0, Op1, Lp, Ob);
  hipLaunchKernelGGL(k_proj_gemm, dim3(8, 64), dim3(256), 0, stream,
                     Ob, wout_t, bout, out);
}

// Round 6
// 470.447 us; speedup vs baseline: 2.2131x; 1.1518x over previous
//
#include <hip/hip_runtime.h>
#include <hip/hip_bf16.h>
#include <stdint.h>

// Round 6: flash register-pressure attack. Residency was reg-capped at
// 2 waves/SIMD (108 VGPR + 64 AGPR = 172/wave). New shape: 16 rows/wave
// (o=32 AGPR, qf=16 VGPR => ~100 regs/wave) x 8 waves (512 thr) = 128
// rows/block (same staging amortization as round 3) -> 4 waves/SIMD.
// KV-split + combine reverted (round 5: +53us of per-block fixed costs,
// zero residency gain). qkv_gemm keeps direct-Vt epilogue (no vtrans).
//
// ws layout:
//   xb      [8192][1024] bf16  @ 0         (dead after qkv -> Ob)
//   wqkv_t  [3072][1024] bf16  @ 16777216
//   wout_t  [1024][1024] bf16  @ 23068672
//   Qs      [16][4096][128]    @ 25165824
//   Ks      [16][4096][128]    @ 41943040
//   Vt      [16][128][4096]    @ 58720256

typedef __attribute__((ext_vector_type(8))) short short8;
typedef __attribute__((ext_vector_type(4))) float f32x4;

#define SCALE_Q 0.03125f

__device__ __forceinline__ unsigned short f2bf(float f) {
  union { float f; unsigned int u; } v;
  v.f = f;
  return (unsigned short)((v.u + 0x7fffu + ((v.u >> 16) & 1u)) >> 16);
}

__device__ __forceinline__ unsigned int pkbf2(float a, float b) {
  __hip_bfloat162 h = __float22bfloat162_rn(make_float2(a, b));
  union { __hip_bfloat162 h; unsigned int u; } c;
  c.h = h;
  return c.u;
}

__device__ __forceinline__ void gload_lds16(const void* g, void* l) {
  __builtin_amdgcn_global_load_lds(
      (const __attribute__((address_space(1))) uint32_t*)(uintptr_t)g,
      (__attribute__((address_space(3))) uint32_t*)(uintptr_t)l, 16, 0, 0);
}

__device__ __forceinline__ f32x4 zero4() {
  f32x4 z; z.x = 0.f; z.y = 0.f; z.z = 0.f; z.w = 0.f; return z;
}

// ---------------- conversions ----------------
__global__ __launch_bounds__(256) void k_cvt_x(const float* __restrict__ in,
                                               unsigned short* __restrict__ out) {
  const int t = blockIdx.x * 256 + threadIdx.x;
  const float4 v = ((const float4*)in)[t];
  ushort4 o;
  o.x = f2bf(v.x); o.y = f2bf(v.y); o.z = f2bf(v.z); o.w = f2bf(v.w);
  ((ushort4*)out)[t] = o;
}

__global__ __launch_bounds__(256) void k_cvt_wt(const float* __restrict__ w,
                                                unsigned short* __restrict__ wt,
                                                int Nn) {
  __shared__ float t[32][33];
  const int n0 = blockIdx.x << 5, k0 = blockIdx.y << 5;
  const int c = threadIdx.x & 31, r8 = threadIdx.x >> 5;
#pragma unroll
  for (int i = 0; i < 4; ++i) {
    const int r = (i << 3) + r8;
    t[r][c] = w[(long)(k0 + r) * Nn + n0 + c];
  }
  __syncthreads();
#pragma unroll
  for (int i = 0; i < 4; ++i) {
    const int r = (i << 3) + r8;
    wt[(long)(n0 + r) * 1024 + k0 + c] = f2bf(t[c][r]);
  }
}

// ---------------- QKV GEMM ----------------
// Q/K tiles: acc^T = mfma(bfr, afr) -> lane reg-quad = 4 consecutive d ->
// packed 8B stores. V tiles: normal orientation -> reg-quad = 4 consecutive
// m (= Vt fast axis) -> writes Vt directly.
__global__ __launch_bounds__(256, 2) void k_qkv_gemm(
    const unsigned short* __restrict__ A,   // [8192][1024]
    const unsigned short* __restrict__ Bt,  // [3072][1024]
    unsigned short* __restrict__ Qs, unsigned short* __restrict__ Ks,
    unsigned short* __restrict__ Vt) {
  __shared__ __align__(16) unsigned short lA[4][128][8];
  __shared__ __align__(16) unsigned short lB[4][128][8];
  const int tid = threadIdx.x;
  const int w = tid >> 6, ln = tid & 63;
  const int m15 = ln & 15, q4 = ln >> 4;
  const int wm = (w >> 1) << 6, wn = (w & 1) << 6;
  const int tn = blockIdx.x, tm = blockIdx.y;
  const int which = tn >> 3;   // 0=Q 1=K 2=V (uniform per block)
  const int h = tn & 7;

  f32x4 acc[4][4];
#pragma unroll
  for (int i = 0; i < 4; ++i)
#pragma unroll
    for (int j = 0; j < 4; ++j) acc[i][j] = zero4();

  if (which == 2) {
    for (int kb = 0; kb < 1024; kb += 32) {
      __syncthreads();
#pragma unroll
      for (int c = 0; c < 2; ++c) {
        const int p = ((c * 4 + w) << 10) + (ln << 4);
        const int g = p >> 11;
        const int r = (p & 2047) >> 4;
        gload_lds16(A + ((long)tm * 128 + r) * 1024 + kb + g * 8,
                    (char*)&lA[0][0][0] + p);
        gload_lds16(Bt + ((long)tn * 128 + r) * 1024 + kb + g * 8,
                    (char*)&lB[0][0][0] + p);
      }
      __syncthreads();
      short8 afr[4], bfr[4];
#pragma unroll
      for (int i = 0; i < 4; ++i)
        afr[i] = *(const short8*)&lA[q4][wm + i * 16 + m15][0];
#pragma unroll
      for (int j = 0; j < 4; ++j)
        bfr[j] = *(const short8*)&lB[q4][wn + j * 16 + m15][0];
#pragma unroll
      for (int i = 0; i < 4; ++i)
#pragma unroll
        for (int j = 0; j < 4; ++j)
          acc[i][j] = __builtin_amdgcn_mfma_f32_16x16x32_bf16(afr[i], bfr[j],
                                                              acc[i][j], 0, 0, 0);
    }
#pragma unroll
    for (int i = 0; i < 4; ++i) {
      const int m0 = (tm << 7) + wm + (i << 4) + (q4 << 2);
      const int b = m0 >> 12, row0 = m0 & 4095;
#pragma unroll
      for (int j = 0; j < 4; ++j) {
        const int dd = wn + (j << 4) + m15;
        const long bh = b * 8 + h;
        uint2 u;
        u.x = pkbf2(acc[i][j][0], acc[i][j][1]);
        u.y = pkbf2(acc[i][j][2], acc[i][j][3]);
        *(uint2*)&Vt[(bh * 128 + dd) * 4096 + row0] = u;
      }
    }
  } else {
    for (int kb = 0; kb < 1024; kb += 32) {
      __syncthreads();
#pragma unroll
      for (int c = 0; c < 2; ++c) {
        const int p = ((c * 4 + w) << 10) + (ln << 4);
        const int g = p >> 11;
        const int r = (p & 2047) >> 4;
        gload_lds16(A + ((long)tm * 128 + r) * 1024 + kb + g * 8,
                    (char*)&lA[0][0][0] + p);
        gload_lds16(Bt + ((long)tn * 128 + r) * 1024 + kb + g * 8,
                    (char*)&lB[0][0][0] + p);
      }
      __syncthreads();
      short8 afr[4], bfr[4];
#pragma unroll
      for (int i = 0; i < 4; ++i)
        afr[i] = *(const short8*)&lA[q4][wm + i * 16 + m15][0];
#pragma unroll
      for (int j = 0; j < 4; ++j)
        bfr[j] = *(const short8*)&lB[q4][wn + j * 16 + m15][0];
#pragma unroll
      for (int i = 0; i < 4; ++i)
#pragma unroll
        for (int j = 0; j < 4; ++j)
          acc[i][j] = __builtin_amdgcn_mfma_f32_16x16x32_bf16(bfr[j], afr[i],
                                                              acc[i][j], 0, 0, 0);
    }
    unsigned short* Dst = (which == 0) ? Qs : Ks;
    const float sc = (which == 0) ? SCALE_Q : 1.0f;
#pragma unroll
    for (int i = 0; i < 4; ++i) {
      const int m = (tm << 7) + wm + (i << 4) + m15;
      const int b = m >> 12, row = m & 4095;
      const long bh = b * 8 + h;
#pragma unroll
      for (int j = 0; j < 4; ++j) {
        const int dd0 = wn + (j << 4) + (q4 << 2);
        uint2 u;
        u.x = pkbf2(acc[i][j][0] * sc, acc[i][j][1] * sc);
        u.y = pkbf2(acc[i][j][2] * sc, acc[i][j][3] * sc);
        *(uint2*)&Dst[(bh * 4096 + row) * 128 + dd0] = u;
      }
    }
  }
}

// ---------------- flash attention (S^T, 128 rows/block, 8 waves) --------
// grid (32 rowblk, 16 bh); 512 thr = 8 waves x 16 rows. ~100 regs/wave
// (32 AGPR o + ~70 VGPR) -> 4 waves/SIMD resident (vs 2 at round 3's 172).
__global__ __launch_bounds__(512, 2) void k_flash(
    const unsigned short* __restrict__ Qs, const unsigned short* __restrict__ Ks,
    const unsigned short* __restrict__ Vt, const int* __restrict__ mask,
    unsigned short* __restrict__ Ob) {
  __shared__ __align__(16) unsigned short lK[16][64][8];   // 16 KB
  __shared__ __align__(16) unsigned short lV[8][128][8];   // 16 KB
  __shared__ __align__(16) unsigned short lP[8][16][72];   // 18 KB

  const int tid = threadIdx.x;
  const int w = tid >> 6, ln = tid & 63;
  const int m15 = ln & 15, q4 = ln >> 4;
  const int rowblk = blockIdx.x, bh = blockIdx.y;
  const int rbase = rowblk * 128 + w * 16;
  const int qrow = rbase + m15;

  const unsigned short* Qbh = Qs + (long)bh * 524288;
  const unsigned short* Kbh = Ks + (long)bh * 524288;
  const unsigned short* Vbh = Vt + (long)bh * 524288;

  short8 qf[4];
#pragma unroll
  for (int kk = 0; kk < 4; ++kk)
    qf[kk] = *(const short8*)(Qbh + (long)qrow * 128 + kk * 32 + q4 * 8);

  f32x4 o[8];
#pragma unroll
  for (int j = 0; j < 8; ++j) o[j] = zero4();
  f32x4 lacc = zero4();

  const bool maskblk = rowblk < 16;

  for (int kv = 0; kv < 4096; kv += 64) {
    __syncthreads();
    // stage K (16KB) and V (16KB); 512 thr x 16B, 2 c-iters each
#pragma unroll
    for (int c = 0; c < 2; ++c) {
      const int p = ((c * 8 + w) << 10) + (ln << 4);
      const int cs = p >> 10;
      const int j = (p & 1023) >> 4;
      gload_lds16(Kbh + (long)(kv + j) * 128 + cs * 8, (char*)&lK[0][0][0] + p);
    }
#pragma unroll
    for (int c = 0; c < 2; ++c) {
      const int p = ((c * 8 + w) << 10) + (ln << 4);
      const int cv = p >> 11;
      const int dv = (p & 2047) >> 4;
      gload_lds16(Vbh + (long)dv * 4096 + kv + cv * 8, (char*)&lV[0][0][0] + p);
    }
    __syncthreads();

    // S^T = K Q^T : s[jt][r] = S[q = qrow][j = kv + jt*16 + q4*4 + r]
    f32x4 s[4];
#pragma unroll
    for (int jt = 0; jt < 4; ++jt) s[jt] = zero4();
#pragma unroll
    for (int jt = 0; jt < 4; ++jt) {
#pragma unroll
      for (int kk = 0; kk < 4; ++kk) {
        const short8 kfr = *(const short8*)&lK[kk * 4 + q4][jt * 16 + m15][0];
        s[jt] = __builtin_amdgcn_mfma_f32_16x16x32_bf16(kfr, qf[kk], s[jt],
                                                        0, 0, 0);
      }
    }

    if (maskblk && kv < 2048) {
#pragma unroll
      for (int jt = 0; jt < 4; ++jt) {
        const int4 mv =
            *(const int4*)&mask[(long)qrow * 2048 + kv + jt * 16 + q4 * 4];
        s[jt].x = mv.x ? s[jt].x : -1e30f;
        s[jt].y = mv.y ? s[jt].y : -1e30f;
        s[jt].z = mv.z ? s[jt].z : -1e30f;
        s[jt].w = mv.w ? s[jt].w : -1e30f;
      }
    }

    // p = exp(s); per-lane l; pack to wave-private LDS as PV A-frags.
#pragma unroll
    for (int jt = 0; jt < 4; ++jt) {
      f32x4 p;
      p.x = __expf(s[jt].x); p.y = __expf(s[jt].y);
      p.z = __expf(s[jt].z); p.w = __expf(s[jt].w);
      lacc.x += p.x; lacc.y += p.y; lacc.z += p.z; lacc.w += p.w;
      uint2 u;
      u.x = pkbf2(p.x, p.y);
      u.y = pkbf2(p.z, p.w);
      *(uint2*)&lP[w][m15][jt * 16 + q4 * 4] = u;
    }
    __asm__ volatile("s_waitcnt lgkmcnt(0)" ::: "memory");

    // O += P @ V
#pragma unroll
    for (int kk2 = 0; kk2 < 2; ++kk2) {
      const short8 pf = *(const short8*)&lP[w][m15][kk2 * 32 + q4 * 8];
#pragma unroll
      for (int jt2 = 0; jt2 < 8; ++jt2) {
        const short8 vf = *(const short8*)&lV[kk2 * 4 + q4][jt2 * 16 + m15][0];
        o[jt2] = __builtin_amdgcn_mfma_f32_16x16x32_bf16(pf, vf, o[jt2],
                                                         0, 0, 0);
      }
    }
  }

  // l: horizontal + across q4 groups (lanes with same m15 share qrow)
  float lh = lacc.x + lacc.y + lacc.z + lacc.w;
  lh += __shfl_xor(lh, 16);
  lh += __shfl_xor(lh, 32);
  const float linv = 1.0f / lh;
  float linv_r[4];
#pragma unroll
  for (int r = 0; r < 4; ++r) linv_r[r] = __shfl(linv, q4 * 4 + r);

  const int b = bh >> 3, h = bh & 7;
#pragma unroll
  for (int r = 0; r < 4; ++r) {
    const int row = rbase + q4 * 4 + r;
    unsigned short* op = Ob + ((long)(b * 4096 + row)) * 1024 + h * 128;
#pragma unroll
    for (int jt2 = 0; jt2 < 8; ++jt2)
      op[jt2 * 16 + m15] = f2bf(o[jt2][r] * linv_r[r]);
  }
}

// ---------------- out projection ----------------
__global__ __launch_bounds__(256, 2) void k_proj_gemm(
    const unsigned short* __restrict__ A,   // [8192][1024]
    const unsigned short* __restrict__ Bt,  // [1024][1024]
    const float* __restrict__ bias, float* __restrict__ Out) {
  __shared__ __align__(16) unsigned short lA[4][128][8];
  __shared__ __align__(16) unsigned short lB[4][128][8];
  const int tid = threadIdx.x;
  const int w = tid >> 6, ln = tid & 63;
  const int m15 = ln & 15, q4 = ln >> 4;
  const int wm = (w >> 1) << 6, wn = (w & 1) << 6;
  const int tn = blockIdx.x, tm = blockIdx.y;

  f32x4 acc[4][4];
#pragma unroll
  for (int i = 0; i < 4; ++i)
#pragma unroll
    for (int j = 0; j < 4; ++j) acc[i][j] = zero4();

  for (int kb = 0; kb < 1024; kb += 32) {
    __syncthreads();
#pragma unroll
    for (int c = 0; c < 2; ++c) {
      const int p = ((c * 4 + w) << 10) + (ln << 4);
      const int g = p >> 11;
      const int r = (p & 2047) >> 4;
      gload_lds16(A + ((long)tm * 128 + r) * 1024 + kb + g * 8,
                  (char*)&lA[0][0][0] + p);
      gload_lds16(Bt + ((long)tn * 128 + r) * 1024 + kb + g * 8,
                  (char*)&lB[0][0][0] + p);
    }
    __syncthreads();
    short8 afr[4], bfr[4];
#pragma unroll
    for (int i = 0; i < 4; ++i)
      afr[i] = *(const short8*)&lA[q4][wm + i * 16 + m15][0];
#pragma unroll
    for (int j = 0; j < 4; ++j)
      bfr[j] = *(const short8*)&lB[q4][wn + j * 16 + m15][0];
#pragma unroll
    for (int i = 0; i < 4; ++i)
#pragma unroll
      for (int j = 0; j < 4; ++j)
        acc[i][j] = __builtin_amdgcn_mfma_f32_16x16x32_bf16(afr[i], bfr[j],
                                                            acc[i][j], 0, 0, 0);
  }

#pragma unroll
  for (int i = 0; i < 4; ++i)
#pragma unroll
    for (int r = 0; r < 4; ++r) {
      const int m = (tm << 7) + wm + (i << 4) + (q4 << 2) + r;
#pragma unroll
      for (int j = 0; j < 4; ++j) {
        const int n = (tn << 7) + wn + (j << 4) + m15;
        Out[(long)m * 1024 + n] = acc[i][j][r] + bias[n];
      }
    }
}

extern "C" void kernel_launch(void* const* d_in, const int* in_sizes, int n_in,
                              void* d_out, int out_size, void* d_ws,
                              size_t ws_size, hipStream_t stream) {
  const float* x = (const float*)d_in[0];
  const float* Wqkv = (const float*)d_in[1];
  const float* Wout = (const float*)d_in[2];
  const float* bout = (const float*)d_in[3];
  const int* mask = (const int*)d_in[4];
  float* out = (float*)d_out;

  char* ws = (char*)d_ws;
  unsigned short* xb     = (unsigned short*)(ws);            // later Ob
  unsigned short* wqkv_t = (unsigned short*)(ws + 16777216);
  unsigned short* wout_t = (unsigned short*)(ws + 23068672);
  unsigned short* Qs     = (unsigned short*)(ws + 25165824);
  unsigned short* Ks     = (unsigned short*)(ws + 41943040);
  unsigned short* Vt     = (unsigned short*)(ws + 58720256);
  unsigned short* Ob     = xb;  // xb dead after qkv_gemm

  hipLaunchKernelGGL(k_cvt_x, dim3(8192), dim3(256), 0, stream, x, xb);
  hipLaunchKernelGGL(k_cvt_wt, dim3(96, 32), dim3(256), 0, stream, Wqkv, wqkv_t, 3072);
  hipLaunchKernelGGL(k_cvt_wt, dim3(32, 32), dim3(256), 0, stream, Wout, wout_t, 1024);
  hipLaunchKernelGGL(k_qkv_gemm, dim3(24, 64), dim3(256), 0, stream,
                     xb, wqkv_t, Qs, Ks, Vt);
  hipLaunchKernelGGL(k_flash, dim3(32, 16), dim3(512), 0, stream,
                     Qs, Ks, Vt, mask, Ob);
  hipLaunchKernelGGL(k_proj_gemm, dim3(8, 64), dim3(256), 0, stream,
                     Ob, wout_t, bout, out);
}